// Round 22
// baseline (376.726 us; speedup 1.0000x reference)
//
#include <hip/hip_runtime.h>
#include <hip/hip_bf16.h>

#define NN     500000
#define DIN    256
#define DATT   128
#define NG     4096
#define MT     64
#define NT64   7813       // ceil(NN/64); last tile half-valid
#define NBLOCKS 512       // 2 per CU (16 waves/CU at <=128 VGPR)

typedef __attribute__((ext_vector_type(8))) short short8;
typedef __attribute__((ext_vector_type(4))) float f32x4;

// pack two f32 -> two bf16 (round-half-up)
__device__ __forceinline__ unsigned int pack2bf(float a, float b) {
    unsigned int ua = __float_as_uint(a) + 0x8000u;
    unsigned int ub = __float_as_uint(b) + 0x8000u;
    return __builtin_amdgcn_perm(ub, ua, 0x07060302);  // [ub.b3,ub.b2,ua.b3,ua.b2]
}

// tanh(x) = 1 - 2/(1+e^{2x})
__device__ __forceinline__ float tanh_fast(float v) {
    float e = __expf(2.f * v);
    return 1.f - 2.f * __builtin_amdgcn_rcpf(e + 1.f);
}

// LDS-only barrier: drains DS ops but leaves global loads in flight (T4).
__device__ __forceinline__ void lds_barrier() {
    asm volatile("s_waitcnt lgkmcnt(0)" ::: "memory");
    __builtin_amdgcn_s_barrier();
    asm volatile("" ::: "memory");
}

// one-time: W1 [256][128] fp32 -> W1t [128][256] bf16 (transposed) in d_ws
__global__ void prep_w1t(const float* __restrict__ W1, unsigned short* __restrict__ W1t) {
    int c = blockIdx.x;      // 0..127
    int k = threadIdx.x;     // 0..255
    unsigned int u = __float_as_uint(W1[k * DATT + c]) + 0x8000u;
    W1t[c * DIN + k] = (unsigned short)(u >> 16);
}

// 8-wave (512-thread) pipelined fused kernel, MT=64, 2 blocks/CU.
// == R17's structure with the R18-verified occupancy pin: waves_per_eu(4,4)
// gives the allocator the full 128-VGPR budget. R17's counters showed the
// compiler chose 64 VGPR for this ~119-reg live set and spilled ~480MB/launch
// to scratch (FETCH 878MB vs 540 ideal, WRITE 142MB vs 10) -- the pin is the
// diagnosed remedy, structure otherwise untouched.
// MT=64 halves per-tile fixed costs (2 barrier convoys, prefetch turnaround,
// attn combine) vs the 137us MT=32 champion at identical occupancy.
// Wave owns 16 h-cols; double-buffered bf16 LDS; t+1 prefetch issued after
// barrier1 stays in flight across both lds_barriers (no vmcnt drain).
// Pooling: scalar thread=dim (acc4 variants cost ~90us in atomic traffic),
// thread-half pools nodes [32h,32h+32), accumulator carried across tiles.
__global__ __attribute__((amdgpu_flat_work_group_size(512, 512), amdgpu_waves_per_eu(4, 4)))
void attnpool_kernel(const float* __restrict__ x,
                     const int* __restrict__ batch,
                     const unsigned short* __restrict__ W1t,
                     const float* __restrict__ b1,
                     const float* __restrict__ W2,
                     const float* __restrict__ b2,
                     float* __restrict__ out)
{
    __shared__ unsigned short xb[2][MT * DIN];   // 2 x 32 KB, XOR-swizzled
    __shared__ float part[8][MT];                // 2 KB

    const int bidx = blockIdx.x;
    const int t0   = (int)(((long long)bidx * NT64) / NBLOCKS);
    const int tEnd = (int)(((long long)(bidx + 1) * NT64) / NBLOCKS);
    if (t0 >= tEnd) return;

    const int tid = threadIdx.x;     // 0..511
    const int w   = tid >> 6;        // wave 0..7
    const int l   = tid & 63;
    const int lr  = l & 15;
    const int lg  = l >> 4;

    // ---- per-block constants: A-frags (W1^T rows 16w..16w+15), biases
    short8 afr[8];
    {
        const unsigned short* A0 = W1t + (16 * w + lr) * DIN;
        #pragma unroll
        for (int kc = 0; kc < 8; ++kc)
            afr[kc] = *reinterpret_cast<const short8*>(A0 + 32 * kc + 8 * lg);
    }
    float4 b1v, w2v;
    {
        int c0 = 16 * w + 4 * lg;
        b1v = *reinterpret_cast<const float4*>(&b1[c0]);
        w2v = *reinterpret_cast<const float4*>(&W2[c0]);
    }
    const float b2s = b2[0];

    // ---- prologue: load tile t0 into pf (8 float4 = 32 VGPR)
    const float4* xg = (const float4*)x;
    float4 pf[8];
    #pragma unroll
    for (int i = 0; i < 8; ++i) {
        int j = tid + i * 512;            // float4-chunk id 0..4095
        long long n = (long long)t0 * MT + (j >> 6);
        pf[i] = (n < NN) ? xg[t0 * 4096 + j] : make_float4(0.f, 0.f, 0.f, 0.f);
    }

    float accum = 0.f;
    int gcur = -1;
    int cur = 0;
    const int half = tid >> 8;            // 0: nodes 0..31, 1: nodes 32..63
    const int d    = tid & 255;           // pooled dim

    for (int t = t0; t < tEnd; ++t) {
        // ---- stage tile t: pf -> xb[cur], bf16 swizzled
        unsigned short* X = xb[cur];
        #pragma unroll
        for (int i = 0; i < 8; ++i) {
            int j = tid + i * 512;        // 0..4095
            int r = j >> 6, cc = j & 63;  // row 0..63
            int byte = r * 512 + ((cc * 8) ^ ((r & 7) << 4));
            *reinterpret_cast<uint2*>(reinterpret_cast<char*>(X) + byte) =
                make_uint2(pack2bf(pf[i].x, pf[i].y), pack2bf(pf[i].z, pf[i].w));
        }
        // per-wave batch ids for tile t (lane l <-> node l)
        int bvt = -1;
        {
            long long n = (long long)t * MT + l;
            if (n < NN) {
                int g = batch[n];
                bvt = ((unsigned)g < NG) ? g : -1;
            }
        }
        lds_barrier();                    // X ready; pf regs free; vmcnt NOT drained

        // ---- issue tile t+1 loads; land before next iteration's pack2bf
        if (t + 1 < tEnd) {
            #pragma unroll
            for (int i = 0; i < 8; ++i) {
                int j = tid + i * 512;
                long long n = (long long)(t + 1) * MT + (j >> 6);
                pf[i] = (n < NN) ? xg[(t + 1) * 4096 + j] : make_float4(0.f, 0.f, 0.f, 0.f);
            }
        }

        // ---- GEMM h^T: acc[ct] = h-cols [16w,16w+16) x nodes [16ct,16ct+16)
        f32x4 acc[4];
        #pragma unroll
        for (int ct = 0; ct < 4; ++ct) acc[ct] = (f32x4){0.f, 0.f, 0.f, 0.f};

        #pragma unroll
        for (int kc = 0; kc < 8; ++kc) {
            int ko = 32 * kc + 8 * lg;
            short8 bfr[4];
            #pragma unroll
            for (int ct = 0; ct < 4; ++ct) {
                int row = 16 * ct + lr;
                int byte = row * 512 + ((ko * 2) ^ ((row & 7) << 4));
                bfr[ct] = *reinterpret_cast<const short8*>(reinterpret_cast<const char*>(X) + byte);
            }
            #pragma unroll
            for (int ct = 0; ct < 4; ++ct)
                acc[ct] = __builtin_amdgcn_mfma_f32_16x16x32_bf16(afr[kc], bfr[ct], acc[ct], 0, 0, 0);
        }

        // ---- attn partials: lane holds h[node=16ct+lr][col=16w+4lg+j]
        #pragma unroll
        for (int ct = 0; ct < 4; ++ct) {
            float p = tanh_fast(acc[ct][0] + b1v.x) * w2v.x
                    + tanh_fast(acc[ct][1] + b1v.y) * w2v.y
                    + tanh_fast(acc[ct][2] + b1v.z) * w2v.z
                    + tanh_fast(acc[ct][3] + b1v.w) * w2v.w;
            p += __shfl_xor(p, 16, 64);
            p += __shfl_xor(p, 32, 64);
            if (lg == 0) part[w][16 * ct + lr] = p;
        }
        lds_barrier();                    // part ready; vmcnt NOT drained

        // attn of node l: sum 8 wave partials (broadcast LDS reads)
        float va = b2s + part[0][l] + part[1][l] + part[2][l] + part[3][l]
                       + part[4][l] + part[5][l] + part[6][l] + part[7][l];

        // ---- pooling: thread-half pools nodes [32h,32h+32), dim d;
        // scalar accumulator carried ACROSS tiles (contiguous sorted range)
        #pragma unroll
        for (int n = 0; n < 32; ++n) {
            int node = 32 * half + n;
            int   g = __builtin_amdgcn_readlane(bvt, node);
            float a = __int_as_float(__builtin_amdgcn_readlane(__float_as_int(va), node));
            if (g != gcur) {              // wave-uniform branch
                if (gcur >= 0) atomicAdd(&out[gcur * DIN + d], accum);
                accum = 0.f;
                gcur = g;
            }
            int byte = node * 512 + ((d * 2) ^ ((node & 7) << 4));
            float xv = __uint_as_float(
                (unsigned int)(*reinterpret_cast<const unsigned short*>(
                    reinterpret_cast<const char*>(X) + byte)) << 16);
            accum = fmaf(a, xv, accum);
        }
        cur ^= 1;
    }
    if (gcur >= 0) atomicAdd(&out[gcur * DIN + d], accum);
}

extern "C" void kernel_launch(void* const* d_in, const int* in_sizes, int n_in,
                              void* d_out, int out_size, void* d_ws, size_t ws_size,
                              hipStream_t stream) {
    const float* x     = (const float*)d_in[0];
    const int*   batch = (const int*)d_in[1];     // int32 (JAX x64 disabled)
    const float* W1 = (const float*)d_in[3];
    const float* b1 = (const float*)d_in[4];
    const float* W2 = (const float*)d_in[5];
    const float* b2 = (const float*)d_in[6];
    float* out = (float*)d_out;
    unsigned short* W1t = (unsigned short*)d_ws;   // 64 KB

    hipMemsetAsync(out, 0, (size_t)NG * DIN * sizeof(float), stream);
    prep_w1t<<<DATT, DIN, 0, stream>>>(W1, W1t);
    attnpool_kernel<<<NBLOCKS, 512, 0, stream>>>(x, batch, W1t, b1, W2, b2, out);
}